// Round 3
// baseline (563.982 us; speedup 1.0000x reference)
//
#include <hip/hip_runtime.h>

#define D 64
#define K 1024
#define NPTS 65536
#define OUT_ELEMS (NPTS * D)
#define PAD4 17  // LDS out-slab row stride in float4 units

// ---------------------------------------------------------------------------
// Prep: transpose embeddings [D][K] into eT [K][D]; enorm[k] = ||e_k||^2 in
// numpy axis-0 order; zero the loss output slot.
// ---------------------------------------------------------------------------
__global__ __launch_bounds__(256) void vq_prep(const float* __restrict__ emb,
                                               float* __restrict__ eT,
                                               float* __restrict__ enorm,
                                               float* __restrict__ loss_out) {
    const int idx = blockIdx.x * 256 + threadIdx.x;  // 0 .. 65535
    const int d = idx >> 10;
    const int k = idx & (K - 1);
    eT[k * D + d] = emb[idx];

    if (idx < K) {
        float s = __fmul_rn(emb[idx], emb[idx]);
        for (int dd = 1; dd < D; ++dd) {
            const float v = emb[dd * K + idx];
            s = __fadd_rn(s, __fmul_rn(v, v));
        }
        enorm[idx] = s;
    }
    if (idx == 0) *loss_out = 0.0f;
}

// numpy pairwise_sum partial: sequential adds of 8 squared terms
__device__ __forceinline__ float sq8(float a, float b, float c, float d,
                                     float e, float f, float g, float h) {
    float r = __fmul_rn(a, a);
    r = __fadd_rn(r, __fmul_rn(b, b));
    r = __fadd_rn(r, __fmul_rn(c, c));
    r = __fadd_rn(r, __fmul_rn(d, d));
    r = __fadd_rn(r, __fmul_rn(e, e));
    r = __fadd_rn(r, __fmul_rn(f, f));
    r = __fadd_rn(r, __fmul_rn(g, g));
    r = __fadd_rn(r, __fmul_rn(h, h));
    return r;
}

// ---------------------------------------------------------------------------
// Main: block = 256 thr = 4 waves, owns 64 points (p = blk*64 + lane; every
// wave's lane L holds point blk*64+L). x row loaded DIRECTLY from global into
// 16 named float4 registers — no LDS copy exists, so the compiler cannot
// rematerialize the reads inside the k-loop (the R1/R2 pathology: VGPR=52,
// x demoted, ~4 loads in flight, latency-bound at 522 us).
// __launch_bounds__(256,1) gives the allocator room for the ~150-reg live set.
// Wave w scans codes [w*256,(w+1)*256); LDS combine; winner rows gathered to
// an LDS slab and written coalesced; wave 0 computes the loss.
// ---------------------------------------------------------------------------
__global__ __launch_bounds__(256, 1) void vq_main(const float* __restrict__ x,
                                                  const float* __restrict__ eT,
                                                  const float* __restrict__ enorm,
                                                  float* __restrict__ out,
                                                  float* __restrict__ loss_out) {
    __shared__ float4 slab[64 * PAD4];   // output staging only
    __shared__ float  sdist[4][64];
    __shared__ int    sidx[4][64];

    const int t    = threadIdx.x;
    const int lane = t & 63;
    const int w    = t >> 6;

    // x row -> named registers, straight from global (L1/L3-resident input).
    const float4* xr = (const float4*)(x + ((size_t)blockIdx.x * 64 + lane) * D);
    const float4 x0 = xr[0],  x1 = xr[1],  x2 = xr[2],  x3 = xr[3];
    const float4 x4 = xr[4],  x5 = xr[5],  x6 = xr[6],  x7 = xr[7];
    const float4 x8 = xr[8],  x9 = xr[9],  x10 = xr[10], x11 = xr[11];
    const float4 x12 = xr[12], x13 = xr[13], x14 = xr[14], x15 = xr[15];

    // A = ||x||^2 replicating numpy pairwise_sum (8 accs, unroll-8, tree).
    const float r0 = sq8(x0.x, x2.x, x4.x, x6.x, x8.x, x10.x, x12.x, x14.x);
    const float r1 = sq8(x0.y, x2.y, x4.y, x6.y, x8.y, x10.y, x12.y, x14.y);
    const float r2 = sq8(x0.z, x2.z, x4.z, x6.z, x8.z, x10.z, x12.z, x14.z);
    const float r3 = sq8(x0.w, x2.w, x4.w, x6.w, x8.w, x10.w, x12.w, x14.w);
    const float r4 = sq8(x1.x, x3.x, x5.x, x7.x, x9.x, x11.x, x13.x, x15.x);
    const float r5 = sq8(x1.y, x3.y, x5.y, x7.y, x9.y, x11.y, x13.y, x15.y);
    const float r6 = sq8(x1.z, x3.z, x5.z, x7.z, x9.z, x11.z, x13.z, x15.z);
    const float r7 = sq8(x1.w, x3.w, x5.w, x7.w, x9.w, x11.w, x13.w, x15.w);
    const float A = __fadd_rn(__fadd_rn(__fadd_rn(r0, r1), __fadd_rn(r2, r3)),
                              __fadd_rn(__fadd_rn(r4, r5), __fadd_rn(r6, r7)));

    // Scan this wave's K-chunk. e-row loads are wave-uniform float4 from the
    // L1/L2-resident transposed codebook; load all 16 up front each iteration
    // so ~16 stay in flight.
    float best = 3.402823466e38f;
    int   bi   = 0;
    const int k0 = w * 256;
    for (int kk = 0; kk < 256; ++kk) {
        const int k = k0 + kk;
        const float4* er = (const float4*)(eT + (size_t)k * D);
        const float4 e0 = er[0],  e1 = er[1],  e2 = er[2],  e3 = er[3];
        const float4 e4 = er[4],  e5 = er[5],  e6 = er[6],  e7 = er[7];
        const float4 e8 = er[8],  e9 = er[9],  e10 = er[10], e11 = er[11];
        const float4 e12 = er[12], e13 = er[13], e14 = er[14], e15 = er[15];
        const float enk = enorm[k];
        float ax = 0.f, ay = 0.f, az = 0.f, aw = 0.f;
#define FSTEP(J) {                                        \
        ax = fmaf(x##J.x, e##J.x, ax);                    \
        ay = fmaf(x##J.y, e##J.y, ay);                    \
        az = fmaf(x##J.z, e##J.z, az);                    \
        aw = fmaf(x##J.w, e##J.w, aw); }
        FSTEP(0) FSTEP(1) FSTEP(2) FSTEP(3)
        FSTEP(4) FSTEP(5) FSTEP(6) FSTEP(7)
        FSTEP(8) FSTEP(9) FSTEP(10) FSTEP(11)
        FSTEP(12) FSTEP(13) FSTEP(14) FSTEP(15)
#undef FSTEP
        const float dot  = __fadd_rn(__fadd_rn(ax, ay), __fadd_rn(az, aw));
        const float dist = __fsub_rn(__fadd_rn(A, enk), __fmul_rn(2.0f, dot));
        if (dist < best) { best = dist; bi = k; }   // strict <: first-index ties
    }

    sdist[w][lane] = best;
    sidx[w][lane]  = bi;
    __syncthreads();

    // 4 threads per point: combine the 4 wave candidates (ascending w =
    // ascending k, strict < keeps first index), gather winner's row chunk
    // into the LDS slab.
    {
        const int p = t >> 2;
        const int c = t & 3;
        float fb = sdist[0][p];
        int   fi = sidx[0][p];
#pragma unroll
        for (int ww = 1; ww < 4; ++ww) {
            const float dv = sdist[ww][p];
            const int   iv = sidx[ww][p];
            if (dv < fb) { fb = dv; fi = iv; }
        }
        const float4* qr = (const float4*)(eT + (size_t)fi * D) + c * 4;
        float4* dst = &slab[p * PAD4 + c * 4];
#pragma unroll
        for (int jj = 0; jj < 4; ++jj) dst[jj] = qr[jj];
    }
    __syncthreads();

    // Coalesced write of the block's output slab (16 KiB).
    float4* og = (float4*)out + (size_t)blockIdx.x * 1024;
#pragma unroll
    for (int s = 0; s < 4; ++s) {
        const int f = s * 256 + t;
        og[f] = slab[(f >> 4) * PAD4 + (f & 15)];
    }

    // Loss: wave 0 only (its lanes own exactly the block's 64 points;
    // compile-time x indices everywhere).
    if (w == 0) {
        const float4* qrow = &slab[lane * PAD4];
        float ls = 0.f;
#define LSTEP(J) { const float4 q = qrow[J];              \
        const float dx = q.x - x##J.x;                    \
        const float dy = q.y - x##J.y;                    \
        const float dz = q.z - x##J.z;                    \
        const float dw = q.w - x##J.w;                    \
        ls = fmaf(dx, dx, ls); ls = fmaf(dy, dy, ls);     \
        ls = fmaf(dz, dz, ls); ls = fmaf(dw, dw, ls); }
        LSTEP(0) LSTEP(1) LSTEP(2) LSTEP(3)
        LSTEP(4) LSTEP(5) LSTEP(6) LSTEP(7)
        LSTEP(8) LSTEP(9) LSTEP(10) LSTEP(11)
        LSTEP(12) LSTEP(13) LSTEP(14) LSTEP(15)
#undef LSTEP
#pragma unroll
        for (int off = 32; off > 0; off >>= 1) ls += __shfl_down(ls, off, 64);
        if (lane == 0)
            atomicAdd(loss_out, ls * (1.25f / (float)OUT_ELEMS));
    }
}

extern "C" void kernel_launch(void* const* d_in, const int* in_sizes, int n_in,
                              void* d_out, int out_size, void* d_ws, size_t ws_size,
                              hipStream_t stream) {
    const float* x   = (const float*)d_in[0];   // [64,32,32,64] fp32
    const float* emb = (const float*)d_in[1];   // [64,1024] fp32
    float* out       = (float*)d_out;           // [quantized | loss]
    float* eT        = (float*)d_ws;            // K*D fp32
    float* enorm     = eT + (size_t)K * D;      // K fp32
    float* loss_out  = out + OUT_ELEMS;

    vq_prep<<<dim3(K * D / 256), dim3(256), 0, stream>>>(emb, eT, enorm, loss_out);
    vq_main<<<dim3(NPTS / 64), dim3(256), 0, stream>>>(x, eT, enorm, out, loss_out);
}

// Round 4
// 192.453 us; speedup vs baseline: 2.9305x; 2.9305x over previous
//
#include <hip/hip_runtime.h>

#define D 64
#define K 1024
#define NPTS 65536
#define OUT_ELEMS (NPTS * D)
#define PAD4 17  // LDS out-slab row stride in float4 units

// ---------------------------------------------------------------------------
// Prep: transpose embeddings [D][K] into eT [K][D]; enorm[k] = ||e_k||^2 in
// numpy axis-0 order; zero the loss output slot.
// ---------------------------------------------------------------------------
__global__ __launch_bounds__(256) void vq_prep(const float* __restrict__ emb,
                                               float* __restrict__ eT,
                                               float* __restrict__ enorm,
                                               float* __restrict__ loss_out) {
    const int idx = blockIdx.x * 256 + threadIdx.x;  // 0 .. 65535
    const int d = idx >> 10;
    const int k = idx & (K - 1);
    eT[k * D + d] = emb[idx];

    if (idx < K) {
        float s = __fmul_rn(emb[idx], emb[idx]);
        for (int dd = 1; dd < D; ++dd) {
            const float v = emb[dd * K + idx];
            s = __fadd_rn(s, __fmul_rn(v, v));
        }
        enorm[idx] = s;
    }
    if (idx == 0) *loss_out = 0.0f;
}

// numpy pairwise_sum partial: sequential adds of 8 squared terms
__device__ __forceinline__ float sq8(float a, float b, float c, float d,
                                     float e, float f, float g, float h) {
    float r = __fmul_rn(a, a);
    r = __fadd_rn(r, __fmul_rn(b, b));
    r = __fadd_rn(r, __fmul_rn(c, c));
    r = __fadd_rn(r, __fmul_rn(d, d));
    r = __fadd_rn(r, __fmul_rn(e, e));
    r = __fadd_rn(r, __fmul_rn(f, f));
    r = __fadd_rn(r, __fmul_rn(g, g));
    r = __fadd_rn(r, __fmul_rn(h, h));
    return r;
}

// Opaque register pin: an asm def cannot be rematerialized, so the compiler
// is forced to keep these values in VGPRs across the k-loop (R1-R3 pathology:
// scheduler remats x loads into the loop to chase occupancy -> VGPR=52,
// ~4 loads in flight, 522 us latency-bound).
#define PIN4(v) asm volatile("" : "+v"(v.x), "+v"(v.y), "+v"(v.z), "+v"(v.w))

// ---------------------------------------------------------------------------
// Main: block = 256 thr = 4 waves, owns 64 points (p = blk*64 + lane; all 4
// waves hold the same 64 points, split-K 4x256). x row pinned in 16 named
// float4 registers via PIN4. Wave index made provably uniform with
// readfirstlane so the e-row loads scalarize to s_load_dwordx16 (SMEM pipe,
// SGPR destination, v_fmac takes one SGPR operand) — VMEM goes quiet after
// the initial x read. LDS combine; coalesced slab write; wave 0 does loss.
// ---------------------------------------------------------------------------
__global__ __launch_bounds__(256, 2) void vq_main(const float* __restrict__ x,
                                                  const float* __restrict__ eT,
                                                  const float* __restrict__ enorm,
                                                  float* __restrict__ out,
                                                  float* __restrict__ loss_out) {
    __shared__ float4 slab[64 * PAD4];   // output staging only
    __shared__ float  sdist[4][64];
    __shared__ int    sidx[4][64];

    const int t    = threadIdx.x;
    const int lane = t & 63;
    const int w    = __builtin_amdgcn_readfirstlane(t >> 6);  // provably wave-uniform

    // x row -> named registers, straight from global, then pinned.
    const float4* xr = (const float4*)(x + ((size_t)blockIdx.x * 64 + lane) * D);
    float4 x0 = xr[0],  x1 = xr[1],  x2 = xr[2],  x3 = xr[3];
    float4 x4 = xr[4],  x5 = xr[5],  x6 = xr[6],  x7 = xr[7];
    float4 x8 = xr[8],  x9 = xr[9],  x10 = xr[10], x11 = xr[11];
    float4 x12 = xr[12], x13 = xr[13], x14 = xr[14], x15 = xr[15];
    PIN4(x0);  PIN4(x1);  PIN4(x2);  PIN4(x3);
    PIN4(x4);  PIN4(x5);  PIN4(x6);  PIN4(x7);
    PIN4(x8);  PIN4(x9);  PIN4(x10); PIN4(x11);
    PIN4(x12); PIN4(x13); PIN4(x14); PIN4(x15);

    // A = ||x||^2 replicating numpy pairwise_sum (8 accs, unroll-8, tree).
    const float r0 = sq8(x0.x, x2.x, x4.x, x6.x, x8.x, x10.x, x12.x, x14.x);
    const float r1 = sq8(x0.y, x2.y, x4.y, x6.y, x8.y, x10.y, x12.y, x14.y);
    const float r2 = sq8(x0.z, x2.z, x4.z, x6.z, x8.z, x10.z, x12.z, x14.z);
    const float r3 = sq8(x0.w, x2.w, x4.w, x6.w, x8.w, x10.w, x12.w, x14.w);
    const float r4 = sq8(x1.x, x3.x, x5.x, x7.x, x9.x, x11.x, x13.x, x15.x);
    const float r5 = sq8(x1.y, x3.y, x5.y, x7.y, x9.y, x11.y, x13.y, x15.y);
    const float r6 = sq8(x1.z, x3.z, x5.z, x7.z, x9.z, x11.z, x13.z, x15.z);
    const float r7 = sq8(x1.w, x3.w, x5.w, x7.w, x9.w, x11.w, x13.w, x15.w);
    const float A = __fadd_rn(__fadd_rn(__fadd_rn(r0, r1), __fadd_rn(r2, r3)),
                              __fadd_rn(__fadd_rn(r4, r5), __fadd_rn(r6, r7)));

    // Scan this wave's K-chunk; e addresses are uniform (function of k only).
    float best = 3.402823466e38f;
    int   bi   = 0;
    const int k0 = w * 256;
    for (int kk = 0; kk < 256; ++kk) {
        const int k = k0 + kk;
        const float4* er = (const float4*)(eT + (size_t)k * D);
        const float4 e0 = er[0],  e1 = er[1],  e2 = er[2],  e3 = er[3];
        const float4 e4 = er[4],  e5 = er[5],  e6 = er[6],  e7 = er[7];
        const float4 e8 = er[8],  e9 = er[9],  e10 = er[10], e11 = er[11];
        const float4 e12 = er[12], e13 = er[13], e14 = er[14], e15 = er[15];
        const float enk = enorm[k];
        float ax = 0.f, ay = 0.f, az = 0.f, aw = 0.f;
#define FSTEP(J) {                                        \
        ax = fmaf(x##J.x, e##J.x, ax);                    \
        ay = fmaf(x##J.y, e##J.y, ay);                    \
        az = fmaf(x##J.z, e##J.z, az);                    \
        aw = fmaf(x##J.w, e##J.w, aw); }
        FSTEP(0) FSTEP(1) FSTEP(2) FSTEP(3)
        FSTEP(4) FSTEP(5) FSTEP(6) FSTEP(7)
        FSTEP(8) FSTEP(9) FSTEP(10) FSTEP(11)
        FSTEP(12) FSTEP(13) FSTEP(14) FSTEP(15)
#undef FSTEP
        const float dot  = __fadd_rn(__fadd_rn(ax, ay), __fadd_rn(az, aw));
        const float dist = __fsub_rn(__fadd_rn(A, enk), __fmul_rn(2.0f, dot));
        if (dist < best) { best = dist; bi = k; }   // strict <: first-index ties
    }

    sdist[w][lane] = best;
    sidx[w][lane]  = bi;
    __syncthreads();

    // 4 threads per point: combine the 4 wave candidates (ascending w =
    // ascending k, strict < keeps first index), gather winner's row chunk
    // into the LDS slab.
    {
        const int p = t >> 2;
        const int c = t & 3;
        float fb = sdist[0][p];
        int   fi = sidx[0][p];
#pragma unroll
        for (int ww = 1; ww < 4; ++ww) {
            const float dv = sdist[ww][p];
            const int   iv = sidx[ww][p];
            if (dv < fb) { fb = dv; fi = iv; }
        }
        const float4* qr = (const float4*)(eT + (size_t)fi * D) + c * 4;
        float4* dst = &slab[p * PAD4 + c * 4];
#pragma unroll
        for (int jj = 0; jj < 4; ++jj) dst[jj] = qr[jj];
    }
    __syncthreads();

    // Coalesced write of the block's output slab (16 KiB).
    float4* og = (float4*)out + (size_t)blockIdx.x * 1024;
#pragma unroll
    for (int s = 0; s < 4; ++s) {
        const int f = s * 256 + t;
        og[f] = slab[(f >> 4) * PAD4 + (f & 15)];
    }

    // Loss: wave 0 only (its lanes own exactly the block's 64 points).
    if (w == 0) {
        const float4* qrow = &slab[lane * PAD4];
        float ls = 0.f;
#define LSTEP(J) { const float4 q = qrow[J];              \
        const float dx = q.x - x##J.x;                    \
        const float dy = q.y - x##J.y;                    \
        const float dz = q.z - x##J.z;                    \
        const float dw = q.w - x##J.w;                    \
        ls = fmaf(dx, dx, ls); ls = fmaf(dy, dy, ls);     \
        ls = fmaf(dz, dz, ls); ls = fmaf(dw, dw, ls); }
        LSTEP(0) LSTEP(1) LSTEP(2) LSTEP(3)
        LSTEP(4) LSTEP(5) LSTEP(6) LSTEP(7)
        LSTEP(8) LSTEP(9) LSTEP(10) LSTEP(11)
        LSTEP(12) LSTEP(13) LSTEP(14) LSTEP(15)
#undef LSTEP
#pragma unroll
        for (int off = 32; off > 0; off >>= 1) ls += __shfl_down(ls, off, 64);
        if (lane == 0)
            atomicAdd(loss_out, ls * (1.25f / (float)OUT_ELEMS));
    }
}

extern "C" void kernel_launch(void* const* d_in, const int* in_sizes, int n_in,
                              void* d_out, int out_size, void* d_ws, size_t ws_size,
                              hipStream_t stream) {
    const float* x   = (const float*)d_in[0];   // [64,32,32,64] fp32
    const float* emb = (const float*)d_in[1];   // [64,1024] fp32
    float* out       = (float*)d_out;           // [quantized | loss]
    float* eT        = (float*)d_ws;            // K*D fp32
    float* enorm     = eT + (size_t)K * D;      // K fp32
    float* loss_out  = out + OUT_ELEMS;

    vq_prep<<<dim3(K * D / 256), dim3(256), 0, stream>>>(emb, eT, enorm, loss_out);
    vq_main<<<dim3(NPTS / 64), dim3(256), 0, stream>>>(x, eT, enorm, out, loss_out);
}

// Round 5
// 184.986 us; speedup vs baseline: 3.0488x; 1.0404x over previous
//
#include <hip/hip_runtime.h>

#define D 64
#define K 1024
#define NPTS 65536
#define OUT_ELEMS (NPTS * D)
#define PAD4 17  // LDS out-slab row stride in float4 units

typedef float v2f __attribute__((ext_vector_type(2)));

// ---------------------------------------------------------------------------
// Prep: transpose embeddings [D][K] into eT [K][D]; enorm[k] = ||e_k||^2 in
// numpy axis-0 order; zero the loss output slot.
// ---------------------------------------------------------------------------
__global__ __launch_bounds__(256) void vq_prep(const float* __restrict__ emb,
                                               float* __restrict__ eT,
                                               float* __restrict__ enorm,
                                               float* __restrict__ loss_out) {
    const int idx = blockIdx.x * 256 + threadIdx.x;  // 0 .. 65535
    const int d = idx >> 10;
    const int k = idx & (K - 1);
    eT[k * D + d] = emb[idx];

    if (idx < K) {
        float s = __fmul_rn(emb[idx], emb[idx]);
        for (int dd = 1; dd < D; ++dd) {
            const float v = emb[dd * K + idx];
            s = __fadd_rn(s, __fmul_rn(v, v));
        }
        enorm[idx] = s;
    }
    if (idx == 0) *loss_out = 0.0f;
}

// numpy pairwise_sum partial: sequential adds of 8 squared terms
__device__ __forceinline__ float sq8(float a, float b, float c, float d,
                                     float e, float f, float g, float h) {
    float r = __fmul_rn(a, a);
    r = __fadd_rn(r, __fmul_rn(b, b));
    r = __fadd_rn(r, __fmul_rn(c, c));
    r = __fadd_rn(r, __fmul_rn(d, d));
    r = __fadd_rn(r, __fmul_rn(e, e));
    r = __fadd_rn(r, __fmul_rn(f, f));
    r = __fadd_rn(r, __fmul_rn(g, g));
    r = __fadd_rn(r, __fmul_rn(h, h));
    return r;
}

// Opaque register pin: an asm def cannot be rematerialized -> x stays in VGPRs.
#define PIN2(v) asm volatile("" : "+v"(v))

// ---------------------------------------------------------------------------
// Main: block = 512 thr = 8 waves, owns 64 points (p = blk*64 + lane; all 8
// waves hold the same 64 points, split-K 8x128). 1024 blocks -> 4 blocks/CU
// = 32 waves/CU (R4 had 16: grid was the occupancy cap at VALUBusy 56%).
// x row pinned as 32 named v2f pairs. e-rows scalarized (readfirstlane ->
// s_load_dwordx16, SGPR-resident). Dot product uses packed fp32 FMA
// (v_pk_fma_f32 via __builtin_elementwise_fma on v2f): the (ax,ay)/(az,aw)
// accumulator pairs are independent chains, so packing is bit-identical to
// R4's scalar fmaf order. LDS combine (ascending w = ascending k keeps the
// first-index tie-break); coalesced slab write; wave 0 computes the loss.
// ---------------------------------------------------------------------------
__global__ __launch_bounds__(512, 4) void vq_main(const float* __restrict__ x,
                                                  const float* __restrict__ eT,
                                                  const float* __restrict__ enorm,
                                                  float* __restrict__ out,
                                                  float* __restrict__ loss_out) {
    __shared__ float4 slab[64 * PAD4];   // output staging only (17 KiB)
    __shared__ float  sdist[8][64];
    __shared__ int    sidx[8][64];

    const int t    = threadIdx.x;
    const int lane = t & 63;
    const int w    = __builtin_amdgcn_readfirstlane(t >> 6);  // 0..7, uniform

    // x row -> 16 float4 vector loads, then repacked into 32 named v2f pairs
    // (pair j of float4 J is contiguous, so this is register-coalescable).
    const float4* xr = (const float4*)(x + ((size_t)blockIdx.x * 64 + lane) * D);
    const float4 t0 = xr[0],  t1 = xr[1],  t2 = xr[2],  t3 = xr[3];
    const float4 t4 = xr[4],  t5 = xr[5],  t6 = xr[6],  t7 = xr[7];
    const float4 t8 = xr[8],  t9 = xr[9],  t10 = xr[10], t11 = xr[11];
    const float4 t12 = xr[12], t13 = xr[13], t14 = xr[14], t15 = xr[15];
#define MKPAIR(J) v2f XA##J = {t##J.x, t##J.y}; v2f XB##J = {t##J.z, t##J.w}; \
                  PIN2(XA##J); PIN2(XB##J)
    MKPAIR(0);  MKPAIR(1);  MKPAIR(2);  MKPAIR(3);
    MKPAIR(4);  MKPAIR(5);  MKPAIR(6);  MKPAIR(7);
    MKPAIR(8);  MKPAIR(9);  MKPAIR(10); MKPAIR(11);
    MKPAIR(12); MKPAIR(13); MKPAIR(14); MKPAIR(15);
#undef MKPAIR

    // A = ||x||^2 replicating numpy pairwise_sum (same arg order as R4).
    const float r0 = sq8(XA0.x, XA2.x, XA4.x, XA6.x, XA8.x, XA10.x, XA12.x, XA14.x);
    const float r1 = sq8(XA0.y, XA2.y, XA4.y, XA6.y, XA8.y, XA10.y, XA12.y, XA14.y);
    const float r2 = sq8(XB0.x, XB2.x, XB4.x, XB6.x, XB8.x, XB10.x, XB12.x, XB14.x);
    const float r3 = sq8(XB0.y, XB2.y, XB4.y, XB6.y, XB8.y, XB10.y, XB12.y, XB14.y);
    const float r4 = sq8(XA1.x, XA3.x, XA5.x, XA7.x, XA9.x, XA11.x, XA13.x, XA15.x);
    const float r5 = sq8(XA1.y, XA3.y, XA5.y, XA7.y, XA9.y, XA11.y, XA13.y, XA15.y);
    const float r6 = sq8(XB1.x, XB3.x, XB5.x, XB7.x, XB9.x, XB11.x, XB13.x, XB15.x);
    const float r7 = sq8(XB1.y, XB3.y, XB5.y, XB7.y, XB9.y, XB11.y, XB13.y, XB15.y);
    const float A = __fadd_rn(__fadd_rn(__fadd_rn(r0, r1), __fadd_rn(r2, r3)),
                              __fadd_rn(__fadd_rn(r4, r5), __fadd_rn(r6, r7)));

    // Scan this wave's 128-code chunk; e addresses uniform (function of k).
    float best = 3.402823466e38f;
    int   bi   = 0;
    const int k0 = w * 128;
    for (int kk = 0; kk < 128; ++kk) {
        const int k = k0 + kk;
        const float4* er = (const float4*)(eT + (size_t)k * D);
        const float4 e0 = er[0],  e1 = er[1],  e2 = er[2],  e3 = er[3];
        const float4 e4 = er[4],  e5 = er[5],  e6 = er[6],  e7 = er[7];
        const float4 e8 = er[8],  e9 = er[9],  e10 = er[10], e11 = er[11];
        const float4 e12 = er[12], e13 = er[13], e14 = er[14], e15 = er[15];
        const float enk = enorm[k];
        v2f acc0 = {0.f, 0.f};   // (ax, ay) chain — same pairing as R4
        v2f acc1 = {0.f, 0.f};   // (az, aw) chain
#define FSTEP(J) {                                                   \
        const v2f ea = {e##J.x, e##J.y};                             \
        const v2f eb = {e##J.z, e##J.w};                             \
        acc0 = __builtin_elementwise_fma(XA##J, ea, acc0);           \
        acc1 = __builtin_elementwise_fma(XB##J, eb, acc1); }
        FSTEP(0) FSTEP(1) FSTEP(2) FSTEP(3)
        FSTEP(4) FSTEP(5) FSTEP(6) FSTEP(7)
        FSTEP(8) FSTEP(9) FSTEP(10) FSTEP(11)
        FSTEP(12) FSTEP(13) FSTEP(14) FSTEP(15)
#undef FSTEP
        const float dot  = __fadd_rn(__fadd_rn(acc0.x, acc0.y),
                                     __fadd_rn(acc1.x, acc1.y));
        const float dist = __fsub_rn(__fadd_rn(A, enk), __fmul_rn(2.0f, dot));
        if (dist < best) { best = dist; bi = k; }   // strict <: first-index ties
    }

    sdist[w][lane] = best;
    sidx[w][lane]  = bi;
    __syncthreads();

    // First 256 threads: 4 threads per point combine the 8 wave candidates
    // (ascending w = ascending k, strict < keeps the first index), gather
    // the winner's row chunk into the LDS slab.
    if (t < 256) {
        const int p = t >> 2;
        const int c = t & 3;
        float fb = sdist[0][p];
        int   fi = sidx[0][p];
#pragma unroll
        for (int ww = 1; ww < 8; ++ww) {
            const float dv = sdist[ww][p];
            const int   iv = sidx[ww][p];
            if (dv < fb) { fb = dv; fi = iv; }
        }
        const float4* qr = (const float4*)(eT + (size_t)fi * D) + c * 4;
        float4* dst = &slab[p * PAD4 + c * 4];
#pragma unroll
        for (int jj = 0; jj < 4; ++jj) dst[jj] = qr[jj];
    }
    __syncthreads();

    // Coalesced write of the block's output slab (16 KiB, 512 thr x 2 f4).
    float4* og = (float4*)out + (size_t)blockIdx.x * 1024;
#pragma unroll
    for (int s = 0; s < 2; ++s) {
        const int f = s * 512 + t;
        og[f] = slab[(f >> 4) * PAD4 + (f & 15)];
    }

    // Loss: wave 0 only (its lanes own exactly the block's 64 points).
    if (w == 0) {
        const float4* qrow = &slab[lane * PAD4];
        float ls = 0.f;
#define LSTEP(J) { const float4 q = qrow[J];              \
        const float dx = q.x - XA##J.x;                   \
        const float dy = q.y - XA##J.y;                   \
        const float dz = q.z - XB##J.x;                   \
        const float dw = q.w - XB##J.y;                   \
        ls = fmaf(dx, dx, ls); ls = fmaf(dy, dy, ls);     \
        ls = fmaf(dz, dz, ls); ls = fmaf(dw, dw, ls); }
        LSTEP(0) LSTEP(1) LSTEP(2) LSTEP(3)
        LSTEP(4) LSTEP(5) LSTEP(6) LSTEP(7)
        LSTEP(8) LSTEP(9) LSTEP(10) LSTEP(11)
        LSTEP(12) LSTEP(13) LSTEP(14) LSTEP(15)
#undef LSTEP
#pragma unroll
        for (int off = 32; off > 0; off >>= 1) ls += __shfl_down(ls, off, 64);
        if (lane == 0)
            atomicAdd(loss_out, ls * (1.25f / (float)OUT_ELEMS));
    }
}

extern "C" void kernel_launch(void* const* d_in, const int* in_sizes, int n_in,
                              void* d_out, int out_size, void* d_ws, size_t ws_size,
                              hipStream_t stream) {
    const float* x   = (const float*)d_in[0];   // [64,32,32,64] fp32
    const float* emb = (const float*)d_in[1];   // [64,1024] fp32
    float* out       = (float*)d_out;           // [quantized | loss]
    float* eT        = (float*)d_ws;            // K*D fp32
    float* enorm     = eT + (size_t)K * D;      // K fp32
    float* loss_out  = out + OUT_ELEMS;

    vq_prep<<<dim3(K * D / 256), dim3(256), 0, stream>>>(emb, eT, enorm, loss_out);
    vq_main<<<dim3(NPTS / 64), dim3(512), 0, stream>>>(x, eT, enorm, out, loss_out);
}